// Round 7
// baseline (104.876 us; speedup 1.0000x reference)
//
#include <hip/hip_runtime.h>
#include <hip/hip_bf16.h>
#include <math.h>

typedef __attribute__((ext_vector_type(8))) short bf16x8;
typedef __attribute__((ext_vector_type(4))) short bf16x4;
typedef __attribute__((ext_vector_type(4))) float f32x4;

#define MFMA32 __builtin_amdgcn_mfma_f32_16x16x32_bf16
#define MFMA16 __builtin_amdgcn_mfma_f32_16x16x16bf16_1k

#define QSCALE 0.25503485964546277f  // (1/sqrt(32)) * log2(e)

__device__ inline short bfbits(float f) {
  union { float f; unsigned u; } v; v.f = f;
  unsigned r = v.u + 0x7fffu + ((v.u >> 16) & 1u);
  return (short)(r >> 16);
}
__device__ inline float bf2f(unsigned short u) {
  union { unsigned u; float f; } v; v.u = ((unsigned)u) << 16; return v.f;
}
__device__ inline void gll16(const void* g, void* l) {
  __builtin_amdgcn_global_load_lds(
      (const __attribute__((address_space(1))) unsigned*)g,
      (__attribute__((address_space(3))) unsigned*)l, 16, 0, 0);
}
// pack 4 f32 -> bf16x4 via v_cvt_pk_bf16_f32 (RTNE)
__device__ inline bf16x4 pk4(float e0, float e1, float e2, float e3) {
  unsigned lo, hi;
  asm("v_cvt_pk_bf16_f32 %0, %1, %2" : "=v"(lo) : "v"(e0), "v"(e1));
  asm("v_cvt_pk_bf16_f32 %0, %1, %2" : "=v"(hi) : "v"(e2), "v"(e3));
  union { unsigned u[2]; bf16x4 v; } cv;
  cv.u[0] = lo; cv.u[1] = hi;
  return cv.v;
}

// ---------------------------------------------------------------------------
// wconv: Wt[col][k] bf16 (cols 0..255 gate, 256..1023 qkv w/ q-cols pre-scaled
// by QSCALE); Woutt[col][k] bf16.
// ---------------------------------------------------------------------------
__global__ __launch_bounds__(256) void wconv_kernel(
    const float* __restrict__ Wg, const float* __restrict__ Wqkv,
    const float* __restrict__ Wout, short* __restrict__ Wt,
    short* __restrict__ Woutt) {
  int idx = blockIdx.x * 256 + threadIdx.x;
  if (idx < 1024 * 256) {
    int col = idx >> 8, k = idx & 255;
    float v;
    if (col < 256) {
      v = Wg[k * 256 + col];
    } else {
      int wc = col - 256;
      v = Wqkv[k * 768 + wc];
      if ((wc % 96) < 32) v *= QSCALE;
    }
    Wt[idx] = bfbits(v);
  } else {
    int j = idx - 1024 * 256;
    int col = j >> 8, k = j & 255;
    Woutt[j] = bfbits(Wout[k * 256 + col]);
  }
}

// ---------------------------------------------------------------------------
// bias_bf[h][r][p] = bf16( sum_z pair[r][p][z] * bproj[z][h] )
// ---------------------------------------------------------------------------
__global__ __launch_bounds__(256) void bias_kernel(
    const float* __restrict__ pair, const float* __restrict__ bproj,
    short* __restrict__ bias_bf) {
  __shared__ float bp[128 * 8];
  int t = threadIdx.x;
  for (int i = t; i < 128 * 8; i += 256) bp[i] = bproj[i];
  __syncthreads();
  int idx = blockIdx.x * 256 + t;
  const float4* src = (const float4*)(pair + (size_t)idx * 128);
  float acc[8] = {};
#pragma unroll
  for (int z4 = 0; z4 < 32; ++z4) {
    float4 v = src[z4];
    const float* b0 = &bp[z4 * 32];
#pragma unroll
    for (int h = 0; h < 8; ++h) {
      acc[h] += v.x * b0[h] + v.y * b0[8 + h] +
                v.z * b0[16 + h] + v.w * b0[24 + h];
    }
  }
#pragma unroll
  for (int h = 0; h < 8; ++h)
    bias_bf[(size_t)h * 65536 + idx] = bfbits(acc[h]);
}

// ---------------------------------------------------------------------------
// gemm_fused2: X[32768,256]f32 @ Wt^T -> gate(sigmoid,bf16) | qkv(bf16)
// 2048 blocks (256 m x 8 n via XCD-chunk swizzle), 256 thr (4 waves 2x2),
// tile 128x128, BK=32, dbuf A (reg-staged f32->bf16) + dbuf B (gll16).
// LDS 32KB -> ~3 blocks/CU.
// ---------------------------------------------------------------------------
__global__ __launch_bounds__(256) void gemm_fused2(
    const float* __restrict__ X, const short* __restrict__ Wt,
    short* __restrict__ gate_bf, short* __restrict__ qkv_bf) {
  __shared__ short As[2][128 * 32];  // 2 x 8KB
  __shared__ short Bs[2][128 * 32];  // 2 x 8KB
  int t = threadIdx.x;
  int lane = t & 63, wid = t >> 6;
  int lq = lane & 15, lg = lane >> 4;
  int wm = wid >> 1, wn = wid & 1;

  // XCD-chunk swizzle: each XCD owns 32 contiguous m-panels x all 8 n-tiles
  int flat = blockIdx.x;
  int xcd = flat & 7, local = flat >> 3;
  int bx = xcd * 32 + (local & 31);
  int ny = local >> 5;
  int r0 = bx * 128;
  int cW = ny * 128;  // column base in the 1024-wide concat weight

  auto stageA = [&](int kq, int buf) {
    int row = t >> 1, kh = t & 1;
    const float* src = X + (size_t)(r0 + row) * 256 + kq * 32 + kh * 16;
    float4 v0 = *(const float4*)(src);
    float4 v1 = *(const float4*)(src + 4);
    float4 v2 = *(const float4*)(src + 8);
    float4 v3 = *(const float4*)(src + 12);
    bf16x8 a = {bfbits(v0.x), bfbits(v0.y), bfbits(v0.z), bfbits(v0.w),
                bfbits(v1.x), bfbits(v1.y), bfbits(v1.z), bfbits(v1.w)};
    bf16x8 b = {bfbits(v2.x), bfbits(v2.y), bfbits(v2.z), bfbits(v2.w),
                bfbits(v3.x), bfbits(v3.y), bfbits(v3.z), bfbits(v3.w)};
    int x = (row >> 1) & 3;
    int s0 = (kh * 2) ^ x, s1 = (kh * 2 + 1) ^ x;
    *(bf16x8*)((char*)&As[buf][0] + row * 64 + s0 * 16) = a;
    *(bf16x8*)((char*)&As[buf][0] + row * 64 + s1 * 16) = b;
  };

  auto stageB = [&](int kq, int buf) {
#pragma unroll
    for (int c = 0; c < 2; ++c) {
      int D = c * 4096 + t * 16;   // linear LDS byte dest
      int col = D >> 6;
      int sl = ((D >> 4) & 3) ^ ((col >> 1) & 3);  // inverse-swizzled source
      gll16(Wt + (size_t)(cW + col) * 256 + kq * 32 + sl * 8,
            (char*)&Bs[buf][0] + D);
    }
  };

  f32x4 acc[4][4];
#pragma unroll
  for (int a = 0; a < 4; ++a)
#pragma unroll
    for (int b = 0; b < 4; ++b) acc[a][b] = {0.f, 0.f, 0.f, 0.f};

  stageA(0, 0);
  stageB(0, 0);
  __syncthreads();

  for (int kq = 0; kq < 8; ++kq) {
    int buf = kq & 1;
    if (kq < 7) {
      stageA(kq + 1, buf ^ 1);
      stageB(kq + 1, buf ^ 1);
    }
    bf16x8 afr[4], bfr[4];
#pragma unroll
    for (int mf = 0; mf < 4; ++mf) {
      int row = wm * 64 + mf * 16 + lq;
      int sl = lg ^ ((row >> 1) & 3);
      afr[mf] = *(const bf16x8*)((const char*)&As[buf][0] + row * 64 + sl * 16);
    }
#pragma unroll
    for (int nf = 0; nf < 4; ++nf) {
      int col = wn * 64 + nf * 16 + lq;
      int sl = lg ^ ((col >> 1) & 3);
      bfr[nf] = *(const bf16x8*)((const char*)&Bs[buf][0] + col * 64 + sl * 16);
    }
#pragma unroll
    for (int mf = 0; mf < 4; ++mf)
#pragma unroll
      for (int nf = 0; nf < 4; ++nf)
        acc[mf][nf] = MFMA32(afr[mf], bfr[nf], acc[mf][nf], 0, 0, 0);
    __syncthreads();
  }

  if (cW < 256) {  // gate tiles (ny 0,1): sigmoid
#pragma unroll
    for (int mf = 0; mf < 4; ++mf)
#pragma unroll
      for (int nf = 0; nf < 4; ++nf) {
        int col = cW + wn * 64 + nf * 16 + lq;
#pragma unroll
        for (int j = 0; j < 4; ++j) {
          int row = r0 + wm * 64 + mf * 16 + lg * 4 + j;
          float v = acc[mf][nf][j];
          float sg = __builtin_amdgcn_rcpf(1.f + __expf(-v));
          gate_bf[(size_t)row * 256 + col] = bfbits(sg);
        }
      }
  } else {  // qkv tiles (ny 2..7)
    int cb = cW - 256;
#pragma unroll
    for (int mf = 0; mf < 4; ++mf)
#pragma unroll
      for (int nf = 0; nf < 4; ++nf) {
        int col = cb + wn * 64 + nf * 16 + lq;
#pragma unroll
        for (int j = 0; j < 4; ++j) {
          int row = r0 + wm * 64 + mf * 16 + lg * 4 + j;
          qkv_bf[(size_t)row * 768 + col] = bfbits(acc[mf][nf][j]);
        }
      }
  }
}

// ---------------------------------------------------------------------------
// attn v4: one block per (s,h), 512 thr (8 waves x 32 rows).
// K in LDS (gll16, slot-swizzled); V^T in LDS.
// simT = K@Q^T; E = exp2(simT) via v_exp + v_cvt_pk_bf16_f32;
// attend = (E@V)*rcp(E@1) + bias@V (bias@V via 16x16x32 MFMA);
// epilogue via LDS bounce, coalesced gate-mul + store.
// ---------------------------------------------------------------------------
__global__ __launch_bounds__(512, 4) void attn_mfma4(
    const short* __restrict__ qkv, const short* __restrict__ bias_bf,
    const short* __restrict__ gate_bf, short* __restrict__ attn_bf) {
  int s = blockIdx.x, h = blockIdx.y;
  __shared__ short Ks[8192];       // [256 p][4 slots of 16B], slot-swizzled
  __shared__ short Vt[32][260];    // V^T [c][p]
  short* Res = Ks;                 // reused after PV (barrier-protected)
  int t = threadIdx.x;
  int lane = t & 63, wid = t >> 6;
  int lq = lane & 15, lg = lane >> 4;
  const short* qkv_s = qkv + (size_t)s * 196608 + h * 96;

  // stage K: LDS linear dest, pre-swizzled global source (slot^((p>>1)&3))
#pragma unroll
  for (int q = 0; q < 2; ++q) {
    int off = wid * 2048 + q * 1024 + lane * 16;  // byte offset in Ks
    int p = off >> 6;
    int slot = (off >> 4) & 3;
    int cg = slot ^ ((p >> 1) & 3);
    gll16(qkv_s + p * 768 + 32 + cg * 8, (char*)Ks + wid * 2048 + q * 1024);
  }
  // stage V^T (register transpose)
  {
    int p = t >> 1, hf = t & 1;
    const short* src = qkv_s + p * 768 + 64 + hf * 16;
    bf16x8 v0 = *(const bf16x8*)src;
    bf16x8 v1 = *(const bf16x8*)(src + 8);
#pragma unroll
    for (int i = 0; i < 8; ++i) {
      Vt[hf * 16 + i][p] = v0[i];
      Vt[hf * 16 + 8 + i][p] = v1[i];
    }
  }

  int rbase = wid * 32;
  bf16x8 qf0 = *(const bf16x8*)(qkv_s + (size_t)(rbase + lq) * 768 + lg * 8);
  bf16x8 qf1 = *(const bf16x8*)(qkv_s + (size_t)(rbase + 16 + lq) * 768 + lg * 8);
  const short* bb0 =
      bias_bf + ((size_t)h * 256 + rbase + lq) * 256 + lg * 8;  // 16B frags
  const short* bb1 = bb0 + 16 * 256;

  f32x4 U[2][2], BV[2][2], L[2];
#pragma unroll
  for (int ri = 0; ri < 2; ++ri) {
    L[ri] = {0.f, 0.f, 0.f, 0.f};
#pragma unroll
    for (int ct = 0; ct < 2; ++ct) {
      U[ri][ct] = {0.f, 0.f, 0.f, 0.f};
      BV[ri][ct] = {0.f, 0.f, 0.f, 0.f};
    }
  }
  const bf16x4 ones = {16256, 16256, 16256, 16256};  // bf16 1.0

  __syncthreads();

#pragma unroll
  for (int qtr = 0; qtr < 4; ++qtr) {
    // K fragments (LDS) + bias fragments (global, 16B contiguous)
    bf16x8 kf[4];
    bf16x8 bfa[2][2];  // [chunk][ri]
#pragma unroll
    for (int i = 0; i < 4; ++i) {
      int row = (qtr * 4 + i) * 16 + lq;
      kf[i] = *(const bf16x8*)((const char*)Ks + row * 64 +
                               ((lg ^ ((row >> 1) & 3)) << 4));
    }
#pragma unroll
    for (int c2 = 0; c2 < 2; ++c2) {
      int chunk = qtr * 2 + c2;
      bfa[c2][0] = *(const bf16x8*)(bb0 + chunk * 32);
      bfa[c2][1] = *(const bf16x8*)(bb1 + chunk * 32);
    }

    // QK^T
    f32x4 acc[2][4];
#pragma unroll
    for (int ri = 0; ri < 2; ++ri)
#pragma unroll
      for (int i = 0; i < 4; ++i) acc[ri][i] = {0.f, 0.f, 0.f, 0.f};
    __builtin_amdgcn_s_setprio(1);
#pragma unroll
    for (int i = 0; i < 4; ++i) {
      acc[0][i] = MFMA32(kf[i], qf0, acc[0][i], 0, 0, 0);
      acc[1][i] = MFMA32(kf[i], qf1, acc[1][i], 0, 0, 0);
    }
    // bias@V (independent of QK/exp — fills MFMA pipe under the exp burst)
#pragma unroll
    for (int c2 = 0; c2 < 2; ++c2) {
      int chunk = qtr * 2 + c2;
      bf16x8 v0 = *(const bf16x8*)&Vt[lq][chunk * 32 + lg * 8];
      bf16x8 v1 = *(const bf16x8*)&Vt[16 + lq][chunk * 32 + lg * 8];
      BV[0][0] = MFMA32(bfa[c2][0], v0, BV[0][0], 0, 0, 0);
      BV[0][1] = MFMA32(bfa[c2][0], v1, BV[0][1], 0, 0, 0);
      BV[1][0] = MFMA32(bfa[c2][1], v0, BV[1][0], 0, 0, 0);
      BV[1][1] = MFMA32(bfa[c2][1], v1, BV[1][1], 0, 0, 0);
    }
    __builtin_amdgcn_s_setprio(0);

    // E = exp2(sim); pack to bf16 A-frags via v_cvt_pk
    bf16x4 af[2][4];
#pragma unroll
    for (int ri = 0; ri < 2; ++ri)
#pragma unroll
      for (int i = 0; i < 4; ++i)
        af[ri][i] = pk4(__builtin_amdgcn_exp2f(acc[ri][i][0]),
                        __builtin_amdgcn_exp2f(acc[ri][i][1]),
                        __builtin_amdgcn_exp2f(acc[ri][i][2]),
                        __builtin_amdgcn_exp2f(acc[ri][i][3]));

    // U = E@V, L = E@1
    __builtin_amdgcn_s_setprio(1);
#pragma unroll
    for (int i = 0; i < 4; ++i) {
      int kc = qtr * 4 + i;
      bf16x4 vf0 = *(const bf16x4*)&Vt[lq][kc * 16 + lg * 4];
      bf16x4 vf1 = *(const bf16x4*)&Vt[16 + lq][kc * 16 + lg * 4];
#pragma unroll
      for (int ri = 0; ri < 2; ++ri) {
        U[ri][0] = MFMA16(af[ri][i], vf0, U[ri][0], 0, 0, 0);
        U[ri][1] = MFMA16(af[ri][i], vf1, U[ri][1], 0, 0, 0);
        L[ri]    = MFMA16(af[ri][i], ones, L[ri], 0, 0, 0);
      }
    }
    __builtin_amdgcn_s_setprio(0);
  }

  __syncthreads();  // done reading Ks/Vt; reuse Ks as Res

  // results -> LDS bf16 [256 rows][32 cols]
#pragma unroll
  for (int ri = 0; ri < 2; ++ri) {
    f32x4 inv;
#pragma unroll
    for (int j = 0; j < 4; ++j) inv[j] = __builtin_amdgcn_rcpf(L[ri][j]);
#pragma unroll
    for (int ct = 0; ct < 2; ++ct) {
#pragma unroll
      for (int j = 0; j < 4; ++j) {
        int rl = rbase + ri * 16 + lg * 4 + j;
        Res[rl * 32 + ct * 16 + lq] =
            bfbits(U[ri][ct][j] * inv[j] + BV[ri][ct][j]);
      }
    }
  }
  __syncthreads();

  // coalesced epilogue: gate multiply + 16B stores
  {
    int row = t & 255, hf = t >> 8;
    size_t o = ((size_t)(s * 256 + row)) * 256 + h * 32 + hf * 16;
    bf16x8 r0 = *(const bf16x8*)&Res[row * 32 + hf * 16];
    bf16x8 r1 = *(const bf16x8*)&Res[row * 32 + hf * 16 + 8];
    bf16x8 g0 = *(const bf16x8*)&gate_bf[o];
    bf16x8 g1 = *(const bf16x8*)&gate_bf[o + 8];
    bf16x8 o0, o1;
#pragma unroll
    for (int i = 0; i < 8; ++i) {
      o0[i] = bfbits(bf2f((unsigned short)r0[i]) * bf2f((unsigned short)g0[i]));
      o1[i] = bfbits(bf2f((unsigned short)r1[i]) * bf2f((unsigned short)g1[i]));
    }
    *(bf16x8*)&attn_bf[o] = o0;
    *(bf16x8*)&attn_bf[o + 8] = o1;
  }
}

// ---------------------------------------------------------------------------
// gemm_out: attn_bf[32768,256] @ Woutt^T -> out f32
// ---------------------------------------------------------------------------
__global__ __launch_bounds__(256) void gemm_out2(
    const short* __restrict__ A, const short* __restrict__ Wt,
    float* __restrict__ out) {
  __shared__ short As2[2][128 * 64];
  __shared__ short Bs2[2][128 * 64];
  int t = threadIdx.x;
  int lane = t & 63, wid = t >> 6;
  int lq = lane & 15, lg = lane >> 4;
  int wm = wid >> 1, wn = wid & 1;
  int r0 = blockIdx.x * 128, n0 = blockIdx.y * 128;

  auto stage = [&](int s, int buf) {
#pragma unroll
    for (int q = 0; q < 4; ++q) {
      int P = wid * 4096 + q * 1024 + lane * 16;
      int row = P >> 7, kb = P & 127;
      int klog = kb ^ ((row & 7) << 4);
      gll16((const char*)A + ((size_t)(r0 + row) * 512 + s * 128 + klog),
            (char*)&As2[buf][0] + wid * 4096 + q * 1024);
      gll16((const char*)Wt + ((size_t)(n0 + row) * 512 + s * 128 + klog),
            (char*)&Bs2[buf][0] + wid * 4096 + q * 1024);
    }
  };

  f32x4 acc[4][4];
#pragma unroll
  for (int a = 0; a < 4; ++a)
#pragma unroll
    for (int b = 0; b < 4; ++b) acc[a][b] = {0.f, 0.f, 0.f, 0.f};

  stage(0, 0);
  __syncthreads();
  for (int s = 0; s < 4; ++s) {
    if (s < 3) stage(s + 1, (s + 1) & 1);
    bf16x8 afr[4][2], bfr[4][2];
#pragma unroll
    for (int kcl = 0; kcl < 2; ++kcl) {
#pragma unroll
      for (int mf = 0; mf < 4; ++mf) {
        int row = wm * 64 + mf * 16 + lq;
        int kb = (((kcl << 6) | (lg << 4))) ^ ((row & 7) << 4);
        afr[mf][kcl] = *(const bf16x8*)((const char*)&As2[s & 1][0] + row * 128 + kb);
      }
#pragma unroll
      for (int nf = 0; nf < 4; ++nf) {
        int col = wn * 64 + nf * 16 + lq;
        int kb = (((kcl << 6) | (lg << 4))) ^ ((col & 7) << 4);
        bfr[nf][kcl] = *(const bf16x8*)((const char*)&Bs2[s & 1][0] + col * 128 + kb);
      }
    }
#pragma unroll
    for (int mf = 0; mf < 4; ++mf)
#pragma unroll
      for (int nf = 0; nf < 4; ++nf)
#pragma unroll
        for (int kcl = 0; kcl < 2; ++kcl)
          acc[mf][nf] = MFMA32(afr[mf][kcl], bfr[nf][kcl], acc[mf][nf], 0, 0, 0);
    __syncthreads();
  }
#pragma unroll
  for (int mf = 0; mf < 4; ++mf)
#pragma unroll
    for (int nf = 0; nf < 4; ++nf) {
      int col = n0 + wn * 64 + nf * 16 + lq;
#pragma unroll
      for (int j = 0; j < 4; ++j) {
        int row = r0 + wm * 64 + mf * 16 + lg * 4 + j;
        out[(size_t)row * 256 + col] = acc[mf][nf][j];
      }
    }
}

// ---------------------------------------------------------------------------
extern "C" void kernel_launch(void* const* d_in, const int* in_sizes, int n_in,
                              void* d_out, int out_size, void* d_ws,
                              size_t ws_size, hipStream_t stream) {
  const float* msa  = (const float*)d_in[0];
  const float* pair = (const float*)d_in[1];
  const float* Wg   = (const float*)d_in[2];
  const float* Wqkv = (const float*)d_in[3];
  const float* Wout = (const float*)d_in[4];
  const float* Bp   = (const float*)d_in[5];
  float* out = (float*)d_out;
  short* sw = (short*)d_ws;

  short* bias_bf = sw;                 //   524288 shorts
  short* gate_bf = sw + 524288;        //  8388608
  short* qkv_bf  = sw + 8912896;       // 25165824
  short* attn_bf = sw + 34078720;      //  8388608
  short* Wt_bf   = sw + 42467328;      //   262144
  short* Woutt   = sw + 42729472;      //    65536

  hipLaunchKernelGGL(wconv_kernel, dim3(1280), dim3(256), 0, stream,
                     Wg, Wqkv, Wout, Wt_bf, Woutt);
  hipLaunchKernelGGL(bias_kernel, dim3(256), dim3(256), 0, stream,
                     pair, Bp, bias_bf);
  hipLaunchKernelGGL(gemm_fused2, dim3(2048), dim3(256), 0, stream,
                     msa, Wt_bf, gate_bf, qkv_bf);
  hipLaunchKernelGGL(attn_mfma4, dim3(128, 8), dim3(512), 0, stream,
                     qkv_bf, bias_bf, gate_bf, attn_bf);
  hipLaunchKernelGGL(gemm_out2, dim3(256, 2), dim3(256), 0, stream,
                     attn_bf, Woutt, out);
}

// Round 8
// 104.436 us; speedup vs baseline: 1.0042x; 1.0042x over previous
//
#include <hip/hip_runtime.h>
#include <hip/hip_bf16.h>
#include <math.h>

typedef __attribute__((ext_vector_type(8))) short bf16x8;
typedef __attribute__((ext_vector_type(4))) short bf16x4;
typedef __attribute__((ext_vector_type(4))) float f32x4;

#define MFMA32 __builtin_amdgcn_mfma_f32_16x16x32_bf16
#define MFMA16 __builtin_amdgcn_mfma_f32_16x16x16bf16_1k

#define QSCALE 0.25503485964546277f  // (1/sqrt(32)) * log2(e)

__device__ inline short bfbits(float f) {
  union { float f; unsigned u; } v; v.f = f;
  unsigned r = v.u + 0x7fffu + ((v.u >> 16) & 1u);
  return (short)(r >> 16);
}
__device__ inline float bf2f(unsigned short u) {
  union { unsigned u; float f; } v; v.u = ((unsigned)u) << 16; return v.f;
}
__device__ inline void gll16(const void* g, void* l) {
  __builtin_amdgcn_global_load_lds(
      (const __attribute__((address_space(1))) unsigned*)g,
      (__attribute__((address_space(3))) unsigned*)l, 16, 0, 0);
}
// pack 4 f32 -> bf16x4 via v_cvt_pk_bf16_f32 (RTNE)
__device__ inline bf16x4 pk4(float e0, float e1, float e2, float e3) {
  unsigned lo, hi;
  asm("v_cvt_pk_bf16_f32 %0, %1, %2" : "=v"(lo) : "v"(e0), "v"(e1));
  asm("v_cvt_pk_bf16_f32 %0, %1, %2" : "=v"(hi) : "v"(e2), "v"(e3));
  union { unsigned u[2]; bf16x4 v; } cv;
  cv.u[0] = lo; cv.u[1] = hi;
  return cv.v;
}

// ---------------------------------------------------------------------------
// wconv: Wt[col][k] bf16 (cols 0..255 gate, 256..1023 qkv w/ q-cols pre-scaled
// by QSCALE); Woutt[col][k] bf16.
// ---------------------------------------------------------------------------
__global__ __launch_bounds__(256) void wconv_kernel(
    const float* __restrict__ Wg, const float* __restrict__ Wqkv,
    const float* __restrict__ Wout, short* __restrict__ Wt,
    short* __restrict__ Woutt) {
  int idx = blockIdx.x * 256 + threadIdx.x;
  if (idx < 1024 * 256) {
    int col = idx >> 8, k = idx & 255;
    float v;
    if (col < 256) {
      v = Wg[k * 256 + col];
    } else {
      int wc = col - 256;
      v = Wqkv[k * 768 + wc];
      if ((wc % 96) < 32) v *= QSCALE;
    }
    Wt[idx] = bfbits(v);
  } else {
    int j = idx - 1024 * 256;
    int col = j >> 8, k = j & 255;
    Woutt[j] = bfbits(Wout[k * 256 + col]);
  }
}

// ---------------------------------------------------------------------------
// bias_bf[h][r][p] = bf16( sum_z pair[r][p][z] * bproj[z][h] )
// ---------------------------------------------------------------------------
__global__ __launch_bounds__(256) void bias_kernel(
    const float* __restrict__ pair, const float* __restrict__ bproj,
    short* __restrict__ bias_bf) {
  __shared__ float bp[128 * 8];
  int t = threadIdx.x;
  for (int i = t; i < 128 * 8; i += 256) bp[i] = bproj[i];
  __syncthreads();
  int idx = blockIdx.x * 256 + t;
  const float4* src = (const float4*)(pair + (size_t)idx * 128);
  float acc[8] = {};
#pragma unroll
  for (int z4 = 0; z4 < 32; ++z4) {
    float4 v = src[z4];
    const float* b0 = &bp[z4 * 32];
#pragma unroll
    for (int h = 0; h < 8; ++h) {
      acc[h] += v.x * b0[h] + v.y * b0[8 + h] +
                v.z * b0[16 + h] + v.w * b0[24 + h];
    }
  }
#pragma unroll
  for (int h = 0; h < 8; ++h)
    bias_bf[(size_t)h * 65536 + idx] = bfbits(acc[h]);
}

// ---------------------------------------------------------------------------
// gemm_fused2: X[32768,256]f32 @ Wt^T -> gate(sigmoid,bf16) | qkv(bf16)
// 2048 blocks (256 m x 8 n via XCD-chunk swizzle), 256 thr (4 waves 2x2),
// tile 128x128, BK=32, dbuf A (reg-staged f32->bf16) + dbuf B (gll16).
// LDS 32KB -> ~3 blocks/CU.
// ---------------------------------------------------------------------------
__global__ __launch_bounds__(256) void gemm_fused2(
    const float* __restrict__ X, const short* __restrict__ Wt,
    short* __restrict__ gate_bf, short* __restrict__ qkv_bf) {
  __shared__ short As[2][128 * 32];  // 2 x 8KB
  __shared__ short Bs[2][128 * 32];  // 2 x 8KB
  int t = threadIdx.x;
  int lane = t & 63, wid = t >> 6;
  int lq = lane & 15, lg = lane >> 4;
  int wm = wid >> 1, wn = wid & 1;

  // XCD-chunk swizzle: each XCD owns 32 contiguous m-panels x all 8 n-tiles
  int flat = blockIdx.x;
  int xcd = flat & 7, local = flat >> 3;
  int bx = xcd * 32 + (local & 31);
  int ny = local >> 5;
  int r0 = bx * 128;
  int cW = ny * 128;  // column base in the 1024-wide concat weight

  auto stageA = [&](int kq, int buf) {
    int row = t >> 1, kh = t & 1;
    const float* src = X + (size_t)(r0 + row) * 256 + kq * 32 + kh * 16;
    float4 v0 = *(const float4*)(src);
    float4 v1 = *(const float4*)(src + 4);
    float4 v2 = *(const float4*)(src + 8);
    float4 v3 = *(const float4*)(src + 12);
    bf16x8 a = {bfbits(v0.x), bfbits(v0.y), bfbits(v0.z), bfbits(v0.w),
                bfbits(v1.x), bfbits(v1.y), bfbits(v1.z), bfbits(v1.w)};
    bf16x8 b = {bfbits(v2.x), bfbits(v2.y), bfbits(v2.z), bfbits(v2.w),
                bfbits(v3.x), bfbits(v3.y), bfbits(v3.z), bfbits(v3.w)};
    int x = (row >> 1) & 3;
    int s0 = (kh * 2) ^ x, s1 = (kh * 2 + 1) ^ x;
    *(bf16x8*)((char*)&As[buf][0] + row * 64 + s0 * 16) = a;
    *(bf16x8*)((char*)&As[buf][0] + row * 64 + s1 * 16) = b;
  };

  auto stageB = [&](int kq, int buf) {
#pragma unroll
    for (int c = 0; c < 2; ++c) {
      int D = c * 4096 + t * 16;   // linear LDS byte dest
      int col = D >> 6;
      int sl = ((D >> 4) & 3) ^ ((col >> 1) & 3);  // inverse-swizzled source
      gll16(Wt + (size_t)(cW + col) * 256 + kq * 32 + sl * 8,
            (char*)&Bs[buf][0] + D);
    }
  };

  f32x4 acc[4][4];
#pragma unroll
  for (int a = 0; a < 4; ++a)
#pragma unroll
    for (int b = 0; b < 4; ++b) acc[a][b] = {0.f, 0.f, 0.f, 0.f};

  stageA(0, 0);
  stageB(0, 0);
  __syncthreads();

  for (int kq = 0; kq < 8; ++kq) {
    int buf = kq & 1;
    if (kq < 7) {
      stageA(kq + 1, buf ^ 1);
      stageB(kq + 1, buf ^ 1);
    }
    bf16x8 afr[4], bfr[4];
#pragma unroll
    for (int mf = 0; mf < 4; ++mf) {
      int row = wm * 64 + mf * 16 + lq;
      int sl = lg ^ ((row >> 1) & 3);
      afr[mf] = *(const bf16x8*)((const char*)&As[buf][0] + row * 64 + sl * 16);
    }
#pragma unroll
    for (int nf = 0; nf < 4; ++nf) {
      int col = wn * 64 + nf * 16 + lq;
      int sl = lg ^ ((col >> 1) & 3);
      bfr[nf] = *(const bf16x8*)((const char*)&Bs[buf][0] + col * 64 + sl * 16);
    }
#pragma unroll
    for (int mf = 0; mf < 4; ++mf)
#pragma unroll
      for (int nf = 0; nf < 4; ++nf)
        acc[mf][nf] = MFMA32(afr[mf], bfr[nf], acc[mf][nf], 0, 0, 0);
    __syncthreads();
  }

  if (cW < 256) {  // gate tiles (ny 0,1): sigmoid
#pragma unroll
    for (int mf = 0; mf < 4; ++mf)
#pragma unroll
      for (int nf = 0; nf < 4; ++nf) {
        int col = cW + wn * 64 + nf * 16 + lq;
#pragma unroll
        for (int j = 0; j < 4; ++j) {
          int row = r0 + wm * 64 + mf * 16 + lg * 4 + j;
          float v = acc[mf][nf][j];
          float sg = __builtin_amdgcn_rcpf(1.f + __expf(-v));
          gate_bf[(size_t)row * 256 + col] = bfbits(sg);
        }
      }
  } else {  // qkv tiles (ny 2..7)
    int cb = cW - 256;
#pragma unroll
    for (int mf = 0; mf < 4; ++mf)
#pragma unroll
      for (int nf = 0; nf < 4; ++nf) {
        int col = cb + wn * 64 + nf * 16 + lq;
#pragma unroll
        for (int j = 0; j < 4; ++j) {
          int row = r0 + wm * 64 + mf * 16 + lg * 4 + j;
          qkv_bf[(size_t)row * 768 + col] = bfbits(acc[mf][nf][j]);
        }
      }
  }
}

// ---------------------------------------------------------------------------
// attn v4: one block per (s,h), 512 thr (8 waves x 32 rows).
// K in LDS (gll16, slot-swizzled); V^T in LDS.
// simT = K@Q^T; E = exp2(simT) via v_exp + v_cvt_pk_bf16_f32;
// attend = (E@V)*rcp(E@1) + bias@V (bias@V via 16x16x32 MFMA);
// epilogue via LDS bounce, coalesced gate-mul + store.
// ---------------------------------------------------------------------------
__global__ __launch_bounds__(512, 4) void attn_mfma4(
    const short* __restrict__ qkv, const short* __restrict__ bias_bf,
    const short* __restrict__ gate_bf, short* __restrict__ attn_bf) {
  int s = blockIdx.x, h = blockIdx.y;
  __shared__ short Ks[8192];       // [256 p][4 slots of 16B], slot-swizzled
  __shared__ short Vt[32][260];    // V^T [c][p]
  short* Res = Ks;                 // reused after PV (barrier-protected)
  int t = threadIdx.x;
  int lane = t & 63, wid = t >> 6;
  int lq = lane & 15, lg = lane >> 4;
  const short* qkv_s = qkv + (size_t)s * 196608 + h * 96;

  // stage K: LDS linear dest, pre-swizzled global source (slot^((p>>1)&3))
#pragma unroll
  for (int q = 0; q < 2; ++q) {
    int off = wid * 2048 + q * 1024 + lane * 16;  // byte offset in Ks
    int p = off >> 6;
    int slot = (off >> 4) & 3;
    int cg = slot ^ ((p >> 1) & 3);
    gll16(qkv_s + p * 768 + 32 + cg * 8, (char*)Ks + wid * 2048 + q * 1024);
  }
  // stage V^T (register transpose)
  {
    int p = t >> 1, hf = t & 1;
    const short* src = qkv_s + p * 768 + 64 + hf * 16;
    bf16x8 v0 = *(const bf16x8*)src;
    bf16x8 v1 = *(const bf16x8*)(src + 8);
#pragma unroll
    for (int i = 0; i < 8; ++i) {
      Vt[hf * 16 + i][p] = v0[i];
      Vt[hf * 16 + 8 + i][p] = v1[i];
    }
  }

  int rbase = wid * 32;
  bf16x8 qf0 = *(const bf16x8*)(qkv_s + (size_t)(rbase + lq) * 768 + lg * 8);
  bf16x8 qf1 = *(const bf16x8*)(qkv_s + (size_t)(rbase + 16 + lq) * 768 + lg * 8);
  const short* bb0 =
      bias_bf + ((size_t)h * 256 + rbase + lq) * 256 + lg * 8;  // 16B frags
  const short* bb1 = bb0 + 16 * 256;

  f32x4 U[2][2], BV[2][2], L[2];
#pragma unroll
  for (int ri = 0; ri < 2; ++ri) {
    L[ri] = {0.f, 0.f, 0.f, 0.f};
#pragma unroll
    for (int ct = 0; ct < 2; ++ct) {
      U[ri][ct] = {0.f, 0.f, 0.f, 0.f};
      BV[ri][ct] = {0.f, 0.f, 0.f, 0.f};
    }
  }
  const bf16x4 ones = {16256, 16256, 16256, 16256};  // bf16 1.0

  __syncthreads();

#pragma unroll
  for (int qtr = 0; qtr < 4; ++qtr) {
    // K fragments (LDS) + bias fragments (global, 16B contiguous)
    bf16x8 kf[4];
    bf16x8 bfa[2][2];  // [chunk][ri]
#pragma unroll
    for (int i = 0; i < 4; ++i) {
      int row = (qtr * 4 + i) * 16 + lq;
      kf[i] = *(const bf16x8*)((const char*)Ks + row * 64 +
                               ((lg ^ ((row >> 1) & 3)) << 4));
    }
#pragma unroll
    for (int c2 = 0; c2 < 2; ++c2) {
      int chunk = qtr * 2 + c2;
      bfa[c2][0] = *(const bf16x8*)(bb0 + chunk * 32);
      bfa[c2][1] = *(const bf16x8*)(bb1 + chunk * 32);
    }

    // QK^T
    f32x4 acc[2][4];
#pragma unroll
    for (int ri = 0; ri < 2; ++ri)
#pragma unroll
      for (int i = 0; i < 4; ++i) acc[ri][i] = {0.f, 0.f, 0.f, 0.f};
    __builtin_amdgcn_s_setprio(1);
#pragma unroll
    for (int i = 0; i < 4; ++i) {
      acc[0][i] = MFMA32(kf[i], qf0, acc[0][i], 0, 0, 0);
      acc[1][i] = MFMA32(kf[i], qf1, acc[1][i], 0, 0, 0);
    }
    // bias@V (independent of QK/exp — fills MFMA pipe under the exp burst)
#pragma unroll
    for (int c2 = 0; c2 < 2; ++c2) {
      int chunk = qtr * 2 + c2;
      bf16x8 v0 = *(const bf16x8*)&Vt[lq][chunk * 32 + lg * 8];
      bf16x8 v1 = *(const bf16x8*)&Vt[16 + lq][chunk * 32 + lg * 8];
      BV[0][0] = MFMA32(bfa[c2][0], v0, BV[0][0], 0, 0, 0);
      BV[0][1] = MFMA32(bfa[c2][0], v1, BV[0][1], 0, 0, 0);
      BV[1][0] = MFMA32(bfa[c2][1], v0, BV[1][0], 0, 0, 0);
      BV[1][1] = MFMA32(bfa[c2][1], v1, BV[1][1], 0, 0, 0);
    }
    __builtin_amdgcn_s_setprio(0);

    // E = exp2(sim); pack to bf16 A-frags via v_cvt_pk
    bf16x4 af[2][4];
#pragma unroll
    for (int ri = 0; ri < 2; ++ri)
#pragma unroll
      for (int i = 0; i < 4; ++i)
        af[ri][i] = pk4(__builtin_amdgcn_exp2f(acc[ri][i][0]),
                        __builtin_amdgcn_exp2f(acc[ri][i][1]),
                        __builtin_amdgcn_exp2f(acc[ri][i][2]),
                        __builtin_amdgcn_exp2f(acc[ri][i][3]));

    // U = E@V, L = E@1
    __builtin_amdgcn_s_setprio(1);
#pragma unroll
    for (int i = 0; i < 4; ++i) {
      int kc = qtr * 4 + i;
      bf16x4 vf0 = *(const bf16x4*)&Vt[lq][kc * 16 + lg * 4];
      bf16x4 vf1 = *(const bf16x4*)&Vt[16 + lq][kc * 16 + lg * 4];
#pragma unroll
      for (int ri = 0; ri < 2; ++ri) {
        U[ri][0] = MFMA16(af[ri][i], vf0, U[ri][0], 0, 0, 0);
        U[ri][1] = MFMA16(af[ri][i], vf1, U[ri][1], 0, 0, 0);
        L[ri]    = MFMA16(af[ri][i], ones, L[ri], 0, 0, 0);
      }
    }
    __builtin_amdgcn_s_setprio(0);
  }

  __syncthreads();  // done reading Ks/Vt; reuse Ks as Res

  // results -> LDS bf16 [256 rows][32 cols]
#pragma unroll
  for (int ri = 0; ri < 2; ++ri) {
    f32x4 inv;
#pragma unroll
    for (int j = 0; j < 4; ++j) inv[j] = __builtin_amdgcn_rcpf(L[ri][j]);
#pragma unroll
    for (int ct = 0; ct < 2; ++ct) {
#pragma unroll
      for (int j = 0; j < 4; ++j) {
        int rl = rbase + ri * 16 + lg * 4 + j;
        Res[rl * 32 + ct * 16 + lq] =
            bfbits(U[ri][ct][j] * inv[j] + BV[ri][ct][j]);
      }
    }
  }
  __syncthreads();

  // coalesced epilogue: gate multiply + 16B stores
  {
    int row = t & 255, hf = t >> 8;
    size_t o = ((size_t)(s * 256 + row)) * 256 + h * 32 + hf * 16;
    bf16x8 r0 = *(const bf16x8*)&Res[row * 32 + hf * 16];
    bf16x8 r1 = *(const bf16x8*)&Res[row * 32 + hf * 16 + 8];
    bf16x8 g0 = *(const bf16x8*)&gate_bf[o];
    bf16x8 g1 = *(const bf16x8*)&gate_bf[o + 8];
    bf16x8 o0, o1;
#pragma unroll
    for (int i = 0; i < 8; ++i) {
      o0[i] = bfbits(bf2f((unsigned short)r0[i]) * bf2f((unsigned short)g0[i]));
      o1[i] = bfbits(bf2f((unsigned short)r1[i]) * bf2f((unsigned short)g1[i]));
    }
    *(bf16x8*)&attn_bf[o] = o0;
    *(bf16x8*)&attn_bf[o + 8] = o1;
  }
}

// ---------------------------------------------------------------------------
// gemm_out: attn_bf[32768,256] @ Woutt^T -> out f32
// ---------------------------------------------------------------------------
__global__ __launch_bounds__(256) void gemm_out2(
    const short* __restrict__ A, const short* __restrict__ Wt,
    float* __restrict__ out) {
  __shared__ short As2[2][128 * 64];
  __shared__ short Bs2[2][128 * 64];
  int t = threadIdx.x;
  int lane = t & 63, wid = t >> 6;
  int lq = lane & 15, lg = lane >> 4;
  int wm = wid >> 1, wn = wid & 1;
  int r0 = blockIdx.x * 128, n0 = blockIdx.y * 128;

  auto stage = [&](int s, int buf) {
#pragma unroll
    for (int q = 0; q < 4; ++q) {
      int P = wid * 4096 + q * 1024 + lane * 16;
      int row = P >> 7, kb = P & 127;
      int klog = kb ^ ((row & 7) << 4);
      gll16((const char*)A + ((size_t)(r0 + row) * 512 + s * 128 + klog),
            (char*)&As2[buf][0] + wid * 4096 + q * 1024);
      gll16((const char*)Wt + ((size_t)(n0 + row) * 512 + s * 128 + klog),
            (char*)&Bs2[buf][0] + wid * 4096 + q * 1024);
    }
  };

  f32x4 acc[4][4];
#pragma unroll
  for (int a = 0; a < 4; ++a)
#pragma unroll
    for (int b = 0; b < 4; ++b) acc[a][b] = {0.f, 0.f, 0.f, 0.f};

  stage(0, 0);
  __syncthreads();
  for (int s = 0; s < 4; ++s) {
    if (s < 3) stage(s + 1, (s + 1) & 1);
    bf16x8 afr[4][2], bfr[4][2];
#pragma unroll
    for (int kcl = 0; kcl < 2; ++kcl) {
#pragma unroll
      for (int mf = 0; mf < 4; ++mf) {
        int row = wm * 64 + mf * 16 + lq;
        int kb = (((kcl << 6) | (lg << 4))) ^ ((row & 7) << 4);
        afr[mf][kcl] = *(const bf16x8*)((const char*)&As2[s & 1][0] + row * 128 + kb);
      }
#pragma unroll
      for (int nf = 0; nf < 4; ++nf) {
        int col = wn * 64 + nf * 16 + lq;
        int kb = (((kcl << 6) | (lg << 4))) ^ ((col & 7) << 4);
        bfr[nf][kcl] = *(const bf16x8*)((const char*)&Bs2[s & 1][0] + col * 128 + kb);
      }
    }
#pragma unroll
    for (int mf = 0; mf < 4; ++mf)
#pragma unroll
      for (int nf = 0; nf < 4; ++nf)
#pragma unroll
        for (int kcl = 0; kcl < 2; ++kcl)
          acc[mf][nf] = MFMA32(afr[mf][kcl], bfr[nf][kcl], acc[mf][nf], 0, 0, 0);
    __syncthreads();
  }
#pragma unroll
  for (int mf = 0; mf < 4; ++mf)
#pragma unroll
    for (int nf = 0; nf < 4; ++nf) {
      int col = n0 + wn * 64 + nf * 16 + lq;
#pragma unroll
      for (int j = 0; j < 4; ++j) {
        int row = r0 + wm * 64 + mf * 16 + lg * 4 + j;
        out[(size_t)row * 256 + col] = acc[mf][nf][j];
      }
    }
}

// ---------------------------------------------------------------------------
extern "C" void kernel_launch(void* const* d_in, const int* in_sizes, int n_in,
                              void* d_out, int out_size, void* d_ws,
                              size_t ws_size, hipStream_t stream) {
  const float* msa  = (const float*)d_in[0];
  const float* pair = (const float*)d_in[1];
  const float* Wg   = (const float*)d_in[2];
  const float* Wqkv = (const float*)d_in[3];
  const float* Wout = (const float*)d_in[4];
  const float* Bp   = (const float*)d_in[5];
  float* out = (float*)d_out;
  short* sw = (short*)d_ws;

  short* bias_bf = sw;                 //   524288 shorts
  short* gate_bf = sw + 524288;        //  8388608
  short* qkv_bf  = sw + 8912896;       // 25165824
  short* attn_bf = sw + 34078720;      //  8388608
  short* Wt_bf   = sw + 42467328;      //   262144
  short* Woutt   = sw + 42729472;      //    65536

  hipLaunchKernelGGL(wconv_kernel, dim3(1280), dim3(256), 0, stream,
                     Wg, Wqkv, Wout, Wt_bf, Woutt);
  hipLaunchKernelGGL(bias_kernel, dim3(256), dim3(256), 0, stream,
                     pair, Bp, bias_bf);
  hipLaunchKernelGGL(gemm_fused2, dim3(2048), dim3(256), 0, stream,
                     msa, Wt_bf, gate_bf, qkv_bf);
  hipLaunchKernelGGL(attn_mfma4, dim3(128, 8), dim3(512), 0, stream,
                     qkv_bf, bias_bf, gate_bf, attn_bf);
  hipLaunchKernelGGL(gemm_out2, dim3(256, 2), dim3(256), 0, stream,
                     attn_bf, Woutt, out);
}